// Round 1
// 319.693 us; speedup vs baseline: 1.0164x; 1.0164x over previous
//
#include <hip/hip_runtime.h>
#include <math.h>

// Problem constants (SpiralDeblock)
#define B      16
#define N_IN   7000
#define N_OUT  28000
#define C      64          // C_IN == C_OUT == 64
#define S      9
#define NNZ    (3 * N_OUT) // 84000
#define F      (S * C)     // 576
#define KB     (F / 32)    // 18 k-blocks of 32 for mfma 16x16x32

#define MT     219         // m-tiles in spiral_mfma: ceil(28000/128)

typedef short bf16x8 __attribute__((ext_vector_type(8)));  // 8 bf16 = 4 VGPRs
typedef float f32x4  __attribute__((ext_vector_type(4)));

// fp32 -> bf16 round-to-nearest-even (bit pattern as ushort)
static __device__ __forceinline__ unsigned short f2bf(float f) {
    unsigned u = __float_as_uint(f);
    u += 0x7fffu + ((u >> 16) & 1u);
    return (unsigned short)(u >> 16);
}

// ---------------------------------------------------------------------------
// CSR build: histogram -> exclusive scan -> placement.
// ---------------------------------------------------------------------------
__global__ void hist_kernel(const int* __restrict__ row, int* __restrict__ cnt) {
    int i = blockIdx.x * 256 + threadIdx.x;
    if (i < NNZ) atomicAdd(&cnt[row[i]], 1);
}

// 1024 threads; thread t owns rows [t*28, t*28+28) (t<1000; 1000*28==28000).
__global__ void scan_kernel(const int* __restrict__ cnt,
                            int* __restrict__ offs, int* __restrict__ cursor) {
    __shared__ int tmp[1024];
    const int t = threadIdx.x;
    const int base = t * 28;
    const bool live = (t < 1000);

    int c[28];
    int partial = 0;
    if (live) {
        #pragma unroll
        for (int j = 0; j < 28; ++j) { c[j] = cnt[base + j]; partial += c[j]; }
    }
    tmp[t] = partial;
    __syncthreads();
    #pragma unroll
    for (int off = 1; off < 1024; off <<= 1) {
        int v = (t >= off) ? tmp[t - off] : 0;
        __syncthreads();
        tmp[t] += v;
        __syncthreads();
    }
    if (live) {
        int run = tmp[t] - partial;   // exclusive prefix
        #pragma unroll
        for (int j = 0; j < 28; ++j) {
            offs[base + j]   = run;
            cursor[base + j] = run;
            run += c[j];
        }
        if (t == 999) offs[N_OUT] = run;
    }
}

__global__ void place_kernel(const int* __restrict__ row, const int* __restrict__ col,
                             const float* __restrict__ values,
                             int* __restrict__ cursor,
                             int* __restrict__ ecol, float* __restrict__ eval) {
    int i = blockIdx.x * 256 + threadIdx.x;
    if (i < NNZ) {
        int pos = atomicAdd(&cursor[row[i]], 1);
        ecol[pos] = col[i];
        eval[pos] = values[i];
    }
}

// ---------------------------------------------------------------------------
// Pooling, XCD-pinned by batch-pair: bgroup = blockIdx.x % 8 owns batches
// {bg, bg+8} -> per-XCD x working set = 2 * 1.79 MB = 3.58 MB < 4 MB L2
// (same pinning trick R4 validated on spiral_mfma). Previously every wave
// touched all 16 batch slices (28.7 MB vs 4 MB L2) -> gathers went to L3.
// Wave layout: rsub = lane>>5 (2 rows), bsub = (lane>>4)&1 (2 batches),
// sl = lane&15 (float4 of channels) -> per edge one 16 B load per lane,
// 256 B contiguous per (row,batch) segment. 112K waves give the TLP to
// hide the dependent ecol->x chain.
// ---------------------------------------------------------------------------
__global__ void pool_kernel(const float* __restrict__ x,
                            const int*   __restrict__ ecol,
                            const float* __restrict__ eval,
                            const int*   __restrict__ offs,
                            unsigned short* __restrict__ pooled) {
    const int bg     = blockIdx.x & 7;    // batch group == XCD
    const int rowblk = blockIdx.x >> 3;   // 0..3499
    const int wave = threadIdx.x >> 6;
    const int lane = threadIdx.x & 63;
    const int rsub = lane >> 5;
    const int bsub = (lane >> 4) & 1;
    const int sl   = lane & 15;

    const int r = rowblk * 8 + wave * 2 + rsub;
    const int b = bg + 8 * bsub;

    const int start = offs[r], end = offs[r + 1];

    float4 acc = make_float4(0.f, 0.f, 0.f, 0.f);
    const float* xb = x + (size_t)b * N_IN * C + sl * 4;

    for (int e = start; e < end; ++e) {
        const int   cl = ecol[e];
        const float v  = eval[e];
        const float4 xv = *(const float4*)(xb + (size_t)cl * C);
        acc.x = fmaf(xv.x, v, acc.x);
        acc.y = fmaf(xv.y, v, acc.y);
        acc.z = fmaf(xv.z, v, acc.z);
        acc.w = fmaf(xv.w, v, acc.w);
    }

    ushort4 o;
    o.x = f2bf(acc.x); o.y = f2bf(acc.y);
    o.z = f2bf(acc.z); o.w = f2bf(acc.w);
    *(ushort4*)(pooled + ((size_t)b * N_OUT + r) * C + sl * 4) = o;
}

// ---------------------------------------------------------------------------
// Pack weight (576x64 fp32, row-major [f][o]) into MFMA B-fragment lane order:
// packedW[((kb*4 + nt)*64 + lane)*8 + j] = bf16( W[(kb*32 + quad*8 + j)*64 + nt*16 + lm] )
// ---------------------------------------------------------------------------
__global__ void packw_kernel(const float* __restrict__ w, unsigned short* __restrict__ pw) {
    const int kb   = blockIdx.x;        // 0..17
    const int nt   = threadIdx.x >> 6;  // 0..3
    const int lane = threadIdx.x & 63;
    const int lm   = lane & 15;
    const int quad = lane >> 4;

    unsigned short v[8];
    #pragma unroll
    for (int j = 0; j < 8; ++j) {
        const int k = kb * 32 + quad * 8 + j;
        const int n = nt * 16 + lm;
        v[j] = f2bf(w[(size_t)k * C + n]);
    }
    unsigned short* dst = pw + ((size_t)(kb * 4 + nt) * 64 + lane) * 8;
    #pragma unroll
    for (int j = 0; j < 8; ++j) dst[j] = v[j];
}

// ---------------------------------------------------------------------------
// Gathered GEMM via MFMA 16x16x32 bf16, XCD-pinned by batch (b%8 == L%8).
// R5: kernel was latency-bound (MfmaUtil 9%, Occupancy 25% = 2 waves/SIMD;
// 64x64 wave tile needed acc64 + A-dbuf64 + B-dbuf64 regs). New geometry:
// wave tile 32x64 (acc[2][4] = 32 regs), A double-buffered across s
// (abuf 32 regs), B loaded per-stage (bbuf 32 regs, packedW is L2-hot),
// __launch_bounds__(256,4) -> ~120 unified regs -> 4 waves/SIMD, doubling
// the MFMA issue per SIMD that covers the divergent A-gather latency.
// A-frag: lane holds A[m=lane&15][k=quad*8+j] -> one 16 B load from the
//         gathered pooled row (contiguous bf16 channels), no LDS.
// C/D:    col = lane&15, row = quad*4 + reg.
// ---------------------------------------------------------------------------
__global__ __launch_bounds__(256, 4)
void spiral_mfma(const unsigned short* __restrict__ pooled,
                 const bf16x8*         __restrict__ packedW,
                 const int*            __restrict__ sp,
                 const float*          __restrict__ bias,
                 float*                __restrict__ out) {
    const int L = blockIdx.x;               // 0 .. 16*MT-1
    int b, mtile;
    if (L < 8 * MT) { b = L & 7;                  mtile = L >> 3; }
    else            { b = 8 + ((L - 8 * MT) & 7); mtile = (L - 8 * MT) >> 3; }

    const int wave = threadIdx.x >> 6;
    const int lane = threadIdx.x & 63;
    const int lm   = lane & 15;
    const int quad = lane >> 4;
    const int m_base = mtile * 128 + wave * 32;

    // Lane i (mod 32) pre-loads sp[m_base+i, 0..8]; distributed via shfl.
    int spv[S];
    {
        int r = m_base + (lane & 31);
        if (r >= N_OUT) r = N_OUT - 1;
        #pragma unroll
        for (int s = 0; s < S; ++s) spv[s] = sp[r * S + s];
    }

    const unsigned short* poolb = pooled + (size_t)b * N_OUT * C;

    f32x4 acc[2][4];
    #pragma unroll
    for (int t = 0; t < 2; ++t)
        #pragma unroll
        for (int nt = 0; nt < 4; ++nt)
            acc[t][nt] = (f32x4){0.f, 0.f, 0.f, 0.f};

    int    rowi[2][2];
    bf16x8 abuf[2][2][2];   // [buf][half][t]

    // Prologue: A-frags for s = 0.
    #pragma unroll
    for (int t = 0; t < 2; ++t)
        rowi[0][t] = __shfl(spv[0], t * 16 + lm, 64);
    #pragma unroll
    for (int half = 0; half < 2; ++half) {
        const int c0 = half * 32 + quad * 8;
        #pragma unroll
        for (int t = 0; t < 2; ++t)
            abuf[0][half][t] = *(const bf16x8*)(poolb + (size_t)rowi[0][t] * C + c0);
    }

    #pragma unroll
    for (int s = 0; s < S; ++s) {
        const int cur = s & 1, nxt = cur ^ 1;

        // B-frags for this stage (packedW is 72 KB, L2-resident, coalesced).
        bf16x8 bbuf[2][4];
        #pragma unroll
        for (int half = 0; half < 2; ++half)
            #pragma unroll
            for (int nt = 0; nt < 4; ++nt)
                bbuf[half][nt] = packedW[((s * 2 + half) * 4 + nt) * 64 + lane];

        // Prefetch s+1's A-frags before consuming s.
        if (s + 1 < S) {
            #pragma unroll
            for (int t = 0; t < 2; ++t)
                rowi[nxt][t] = __shfl(spv[s + 1], t * 16 + lm, 64);
            #pragma unroll
            for (int half = 0; half < 2; ++half) {
                const int c0 = half * 32 + quad * 8;
                #pragma unroll
                for (int t = 0; t < 2; ++t)
                    abuf[nxt][half][t] =
                        *(const bf16x8*)(poolb + (size_t)rowi[nxt][t] * C + c0);
            }
        }

        #pragma unroll
        for (int half = 0; half < 2; ++half)
            #pragma unroll
            for (int nt = 0; nt < 4; ++nt)
                #pragma unroll
                for (int t = 0; t < 2; ++t)
                    acc[t][nt] = __builtin_amdgcn_mfma_f32_16x16x32_bf16(
                        abuf[cur][half][t], bbuf[half][nt], acc[t][nt], 0, 0, 0);
    }

    // Epilogue: bias + ELU + store. __expf -> v_exp_f32.
    #pragma unroll
    for (int nt = 0; nt < 4; ++nt) {
        const int n = nt * 16 + lm;
        const float bs = bias[n];
        #pragma unroll
        for (int t = 0; t < 2; ++t) {
            #pragma unroll
            for (int reg = 0; reg < 4; ++reg) {
                const int r = m_base + t * 16 + quad * 4 + reg;
                if (r < N_OUT) {
                    float v = acc[t][nt][reg] + bs;
                    v = v > 0.f ? v : (__expf(v) - 1.0f);
                    out[((size_t)b * N_OUT + r) * C + n] = v;
                }
            }
        }
    }
}

// ---------------------------------------------------------------------------
// Launch.
// Inputs: 0:x 1:values 2:weight 3:bias 4:row 5:col 6:spiral_indices
// ---------------------------------------------------------------------------
extern "C" void kernel_launch(void* const* d_in, const int* in_sizes, int n_in,
                              void* d_out, int out_size, void* d_ws, size_t ws_size,
                              hipStream_t stream) {
    const float* x      = (const float*)d_in[0];
    const float* values = (const float*)d_in[1];
    const float* weight = (const float*)d_in[2];
    const float* bias   = (const float*)d_in[3];
    const int*   row    = (const int*)d_in[4];
    const int*   col    = (const int*)d_in[5];
    const int*   sp     = (const int*)d_in[6];
    float*       out    = (float*)d_out;

    char* ws = (char*)d_ws;
    size_t off = 0;
    unsigned short* pooled  = (unsigned short*)(ws + off); off += (size_t)B * N_OUT * C * 2;      // 57,344,000
    unsigned short* packedW = (unsigned short*)(ws + off); off += (size_t)KB * 4 * 64 * 8 * 2;    // 73,728
    int*   offs   = (int*)(ws + off); off += ((size_t)(N_OUT + 1) * 4 + 124) / 128 * 128;
    int*   cursor = (int*)(ws + off); off += (size_t)N_OUT * 4 + 128;
    int*   cnt    = (int*)(ws + off); off += (size_t)N_OUT * 4 + 128;
    int*   ecol   = (int*)(ws + off); off += (size_t)NNZ * 4;
    float* eval   = (float*)(ws + off); off += (size_t)NNZ * 4;

    // CSR build (cnt must start at zero; ws is poisoned each call).
    (void)hipMemsetAsync(cnt, 0, (size_t)N_OUT * 4, stream);
    hist_kernel <<<(NNZ + 255) / 256, 256, 0, stream>>>(row, cnt);
    scan_kernel <<<1, 1024, 0, stream>>>(cnt, offs, cursor);
    place_kernel<<<(NNZ + 255) / 256, 256, 0, stream>>>(row, col, values, cursor, ecol, eval);

    // Pack weight into MFMA B-fragment order (independent of CSR chain).
    packw_kernel<<<KB, 256, 0, stream>>>(weight, packedW);

    // Pool into bf16, XCD-pinned batch pairs (8 bgroups x 3500 row-blocks).
    pool_kernel<<<(N_OUT / 8) * 8, 256, 0, stream>>>(x, ecol, eval, offs, pooled);

    // Gathered GEMM + bias + ELU (XCD-pinned by batch, 32x64 wave tiles,
    // 4 waves/SIMD).
    spiral_mfma<<<B * MT, 256, 0, stream>>>(pooled,
        reinterpret_cast<const bf16x8*>(packedW), sp, bias, out);
}

// Round 3
// 303.788 us; speedup vs baseline: 1.0696x; 1.0524x over previous
//
#include <hip/hip_runtime.h>
#include <math.h>

// Problem constants (SpiralDeblock)
#define B      16
#define N_IN   7000
#define N_OUT  28000
#define C      64          // C_IN == C_OUT == 64
#define S      9
#define NNZ    (3 * N_OUT) // 84000
#define F      (S * C)     // 576
#define KB     (F / 32)    // 18 k-blocks of 32 for mfma 16x16x32

#define MT     110         // m-tiles in spiral_mfma: ceil(28000/256), 256 rows/block

typedef short bf16x8 __attribute__((ext_vector_type(8)));  // 8 bf16 = 4 VGPRs
typedef float f32x4  __attribute__((ext_vector_type(4)));

// fp32 -> bf16 round-to-nearest-even (bit pattern as ushort)
static __device__ __forceinline__ unsigned short f2bf(float f) {
    unsigned u = __float_as_uint(f);
    u += 0x7fffu + ((u >> 16) & 1u);
    return (unsigned short)(u >> 16);
}

// ---------------------------------------------------------------------------
// CSR build: histogram -> exclusive scan -> placement.
// ---------------------------------------------------------------------------
__global__ void hist_kernel(const int* __restrict__ row, int* __restrict__ cnt) {
    int i = blockIdx.x * 256 + threadIdx.x;
    if (i < NNZ) atomicAdd(&cnt[row[i]], 1);
}

// 1024 threads; thread t owns rows [t*28, t*28+28) (t<1000; 1000*28==28000).
__global__ void scan_kernel(const int* __restrict__ cnt,
                            int* __restrict__ offs, int* __restrict__ cursor) {
    __shared__ int tmp[1024];
    const int t = threadIdx.x;
    const int base = t * 28;
    const bool live = (t < 1000);

    int c[28];
    int partial = 0;
    if (live) {
        #pragma unroll
        for (int j = 0; j < 28; ++j) { c[j] = cnt[base + j]; partial += c[j]; }
    }
    tmp[t] = partial;
    __syncthreads();
    #pragma unroll
    for (int off = 1; off < 1024; off <<= 1) {
        int v = (t >= off) ? tmp[t - off] : 0;
        __syncthreads();
        tmp[t] += v;
        __syncthreads();
    }
    if (live) {
        int run = tmp[t] - partial;   // exclusive prefix
        #pragma unroll
        for (int j = 0; j < 28; ++j) {
            offs[base + j]   = run;
            cursor[base + j] = run;
            run += c[j];
        }
        if (t == 999) offs[N_OUT] = run;
    }
}

__global__ void place_kernel(const int* __restrict__ row, const int* __restrict__ col,
                             const float* __restrict__ values,
                             int* __restrict__ cursor,
                             int* __restrict__ ecol, float* __restrict__ eval) {
    int i = blockIdx.x * 256 + threadIdx.x;
    if (i < NNZ) {
        int pos = atomicAdd(&cursor[row[i]], 1);
        ecol[pos] = col[i];
        eval[pos] = values[i];
    }
}

// ---------------------------------------------------------------------------
// Pooling, XCD-pinned by batch-pair: bgroup = blockIdx.x % 8 owns batches
// {bg, bg+8} -> per-XCD x working set = 3.58 MB < 4 MB L2.
// Per-edge dependent chain (ecol -> x) broken by batching 4 edges:
// 4 independent metadata loads, then 4 independent x-gathers. Pooled
// stores are nontemporal so the 57 MB write stream does not evict the
// pinned x slice from L2.
// ---------------------------------------------------------------------------
__global__ void pool_kernel(const float* __restrict__ x,
                            const int*   __restrict__ ecol,
                            const float* __restrict__ eval,
                            const int*   __restrict__ offs,
                            unsigned short* __restrict__ pooled) {
    const int bg     = blockIdx.x & 7;    // batch group == XCD
    const int rowblk = blockIdx.x >> 3;   // 0..3499
    const int wave = threadIdx.x >> 6;
    const int lane = threadIdx.x & 63;
    const int rsub = lane >> 5;
    const int bsub = (lane >> 4) & 1;
    const int sl   = lane & 15;

    const int r = rowblk * 8 + wave * 2 + rsub;
    const int b = bg + 8 * bsub;

    const int start = offs[r], end = offs[r + 1];

    float4 acc = make_float4(0.f, 0.f, 0.f, 0.f);
    const float* xb = x + (size_t)b * N_IN * C + sl * 4;

    for (int e = start; e < end; e += 4) {
        const int nn = end - e;           // >= 1
        int   cl[4]; float vv[4];
        #pragma unroll
        for (int j = 0; j < 4; ++j) {
            const int ee = (j < nn) ? e + j : e;   // clamp: valid addr, weight 0
            cl[j] = ecol[ee];
            vv[j] = (j < nn) ? eval[ee] : 0.f;
        }
        float4 xv[4];
        #pragma unroll
        for (int j = 0; j < 4; ++j)
            xv[j] = *(const float4*)(xb + (size_t)cl[j] * C);
        #pragma unroll
        for (int j = 0; j < 4; ++j) {
            acc.x = fmaf(xv[j].x, vv[j], acc.x);
            acc.y = fmaf(xv[j].y, vv[j], acc.y);
            acc.z = fmaf(xv[j].z, vv[j], acc.z);
            acc.w = fmaf(xv[j].w, vv[j], acc.w);
        }
    }

    unsigned long long ov =
        (unsigned long long)f2bf(acc.x)
        | ((unsigned long long)f2bf(acc.y) << 16)
        | ((unsigned long long)f2bf(acc.z) << 32)
        | ((unsigned long long)f2bf(acc.w) << 48);
    __builtin_nontemporal_store(ov,
        (unsigned long long*)(pooled + ((size_t)b * N_OUT + r) * C + sl * 4));
}

// ---------------------------------------------------------------------------
// Pack weight (576x64 fp32, row-major [f][o]) into MFMA B-fragment lane order:
// packedW[((kb*4 + nt)*64 + lane)*8 + j] = bf16( W[(kb*32 + quad*8 + j)*64 + nt*16 + lm] )
// ---------------------------------------------------------------------------
__global__ void packw_kernel(const float* __restrict__ w, unsigned short* __restrict__ pw) {
    const int kb   = blockIdx.x;        // 0..17
    const int nt   = threadIdx.x >> 6;  // 0..3
    const int lane = threadIdx.x & 63;
    const int lm   = lane & 15;
    const int quad = lane >> 4;

    unsigned short v[8];
    #pragma unroll
    for (int j = 0; j < 8; ++j) {
        const int k = kb * 32 + quad * 8 + j;
        const int n = nt * 16 + lm;
        v[j] = f2bf(w[(size_t)k * C + n]);
    }
    unsigned short* dst = pw + ((size_t)(kb * 4 + nt) * 64 + lane) * 8;
    #pragma unroll
    for (int j = 0; j < 8; ++j) dst[j] = v[j];
}

// ---------------------------------------------------------------------------
// Gathered GEMM via MFMA 16x16x32 bf16, XCD-pinned by batch (b%8 == L%8).
// R2 theory: kernel was VMEM-pipe throughput bound (R1: occupancy 2x'd ->
// MfmaUtil barely moved). Half the VMEM line traffic was B-fragment
// re-reads of the 72 KB packedW (8 KB per wave per stage). Fix: stage the
// FULL packed B in LDS once per block (72 KB, ds_read_b128 stride-16B =
// conflict-free full-rate pattern); per-stage VMEM is now only the 4
// scattered A-gather loads. Block 512 thr (8 waves x 32 rows = 256 rows),
// 2 blocks/CU (144 KB LDS), 4 waves/SIMD.
// A-frag: lane holds A[m=lane&15][k=quad*8+j] -> one 16 B load from the
//         gathered pooled row (contiguous bf16 channels), double-buffered
//         across s.
// C/D:    col = lane&15, row = quad*4 + reg. Nontemporal out stores.
// ---------------------------------------------------------------------------
__global__ __launch_bounds__(512, 4)
void spiral_mfma(const unsigned short* __restrict__ pooled,
                 const bf16x8*         __restrict__ packedW,
                 const int*            __restrict__ sp,
                 const float*          __restrict__ bias,
                 float*                __restrict__ out) {
    const int L = blockIdx.x;               // 0 .. 16*MT-1
    int b, mtile;
    if (L < 8 * MT) { b = L & 7;                  mtile = L >> 3; }
    else            { b = 8 + ((L - 8 * MT) & 7); mtile = (L - 8 * MT) >> 3; }

    const int wave = threadIdx.x >> 6;      // 0..7
    const int lane = threadIdx.x & 63;
    const int lm   = lane & 15;
    const int quad = lane >> 4;
    const int m_base = mtile * 256 + wave * 32;

    // Stage full packed B (72 KB) into LDS: 512 thr x 16 B x 9 iters.
    // Layout identical to packedW (linear), so index math is unchanged.
    __shared__ bf16x8 bw[KB * 4 * 64];      // 4608 frags = 73728 B
    {
        const int t = threadIdx.x;
        #pragma unroll
        for (int i = 0; i < 9; ++i)
            bw[i * 512 + t] = packedW[i * 512 + t];
    }

    // Lane i (mod 32) pre-loads sp[m_base+i, 0..8]; distributed via shfl.
    int spv[S];
    {
        int r = m_base + (lane & 31);
        if (r >= N_OUT) r = N_OUT - 1;
        #pragma unroll
        for (int s = 0; s < S; ++s) spv[s] = sp[r * S + s];
    }

    const unsigned short* poolb = pooled + (size_t)b * N_OUT * C;

    f32x4 acc[2][4];
    #pragma unroll
    for (int t = 0; t < 2; ++t)
        #pragma unroll
        for (int nt = 0; nt < 4; ++nt)
            acc[t][nt] = (f32x4){0.f, 0.f, 0.f, 0.f};

    int    rowi[2][2];
    bf16x8 abuf[2][2][2];   // [buf][half][t]

    // Prologue: A-frags for s = 0.
    #pragma unroll
    for (int t = 0; t < 2; ++t)
        rowi[0][t] = __shfl(spv[0], t * 16 + lm, 64);
    #pragma unroll
    for (int half = 0; half < 2; ++half) {
        const int c0 = half * 32 + quad * 8;
        #pragma unroll
        for (int t = 0; t < 2; ++t)
            abuf[0][half][t] = *(const bf16x8*)(poolb + (size_t)rowi[0][t] * C + c0);
    }

    __syncthreads();   // B staged (writes above, reads below)

    #pragma unroll
    for (int s = 0; s < S; ++s) {
        const int cur = s & 1, nxt = cur ^ 1;

        // Prefetch s+1's A-frags before consuming s (only VMEM in the loop).
        if (s + 1 < S) {
            #pragma unroll
            for (int t = 0; t < 2; ++t)
                rowi[nxt][t] = __shfl(spv[s + 1], t * 16 + lm, 64);
            #pragma unroll
            for (int half = 0; half < 2; ++half) {
                const int c0 = half * 32 + quad * 8;
                #pragma unroll
                for (int t = 0; t < 2; ++t)
                    abuf[nxt][half][t] =
                        *(const bf16x8*)(poolb + (size_t)rowi[nxt][t] * C + c0);
            }
        }

        // B-frags from LDS per half (keeps live regs ~16 for B).
        #pragma unroll
        for (int half = 0; half < 2; ++half) {
            bf16x8 bb[4];
            #pragma unroll
            for (int nt = 0; nt < 4; ++nt)
                bb[nt] = bw[((s * 2 + half) * 4 + nt) * 64 + lane];
            #pragma unroll
            for (int nt = 0; nt < 4; ++nt)
                #pragma unroll
                for (int t = 0; t < 2; ++t)
                    acc[t][nt] = __builtin_amdgcn_mfma_f32_16x16x32_bf16(
                        abuf[cur][half][t], bb[nt], acc[t][nt], 0, 0, 0);
        }
    }

    // Epilogue: bias + ELU + nontemporal store (out is a pure 114 MB stream;
    // keep pooled/packedW L2-resident).
    #pragma unroll
    for (int nt = 0; nt < 4; ++nt) {
        const int n = nt * 16 + lm;
        const float bs = bias[n];
        #pragma unroll
        for (int t = 0; t < 2; ++t) {
            #pragma unroll
            for (int reg = 0; reg < 4; ++reg) {
                const int r = m_base + t * 16 + quad * 4 + reg;
                if (r < N_OUT) {
                    float v = acc[t][nt][reg] + bs;
                    v = v > 0.f ? v : (__expf(v) - 1.0f);
                    __builtin_nontemporal_store(v,
                        out + ((size_t)b * N_OUT + r) * C + n);
                }
            }
        }
    }
}

// ---------------------------------------------------------------------------
// Launch.
// Inputs: 0:x 1:values 2:weight 3:bias 4:row 5:col 6:spiral_indices
// ---------------------------------------------------------------------------
extern "C" void kernel_launch(void* const* d_in, const int* in_sizes, int n_in,
                              void* d_out, int out_size, void* d_ws, size_t ws_size,
                              hipStream_t stream) {
    const float* x      = (const float*)d_in[0];
    const float* values = (const float*)d_in[1];
    const float* weight = (const float*)d_in[2];
    const float* bias   = (const float*)d_in[3];
    const int*   row    = (const int*)d_in[4];
    const int*   col    = (const int*)d_in[5];
    const int*   sp     = (const int*)d_in[6];
    float*       out    = (float*)d_out;

    char* ws = (char*)d_ws;
    size_t off = 0;
    unsigned short* pooled  = (unsigned short*)(ws + off); off += (size_t)B * N_OUT * C * 2;      // 57,344,000
    unsigned short* packedW = (unsigned short*)(ws + off); off += (size_t)KB * 4 * 64 * 8 * 2;    // 73,728
    int*   offs   = (int*)(ws + off); off += ((size_t)(N_OUT + 1) * 4 + 124) / 128 * 128;
    int*   cursor = (int*)(ws + off); off += (size_t)N_OUT * 4 + 128;
    int*   cnt    = (int*)(ws + off); off += (size_t)N_OUT * 4 + 128;
    int*   ecol   = (int*)(ws + off); off += (size_t)NNZ * 4;
    float* eval   = (float*)(ws + off); off += (size_t)NNZ * 4;

    // CSR build (cnt must start at zero; ws is poisoned each call).
    (void)hipMemsetAsync(cnt, 0, (size_t)N_OUT * 4, stream);
    hist_kernel <<<(NNZ + 255) / 256, 256, 0, stream>>>(row, cnt);
    scan_kernel <<<1, 1024, 0, stream>>>(cnt, offs, cursor);
    place_kernel<<<(NNZ + 255) / 256, 256, 0, stream>>>(row, col, values, cursor, ecol, eval);

    // Pack weight into MFMA B-fragment order (independent of CSR chain).
    packw_kernel<<<KB, 256, 0, stream>>>(weight, packedW);

    // Pool into bf16, XCD-pinned batch pairs (8 bgroups x 3500 row-blocks).
    pool_kernel<<<(N_OUT / 8) * 8, 256, 0, stream>>>(x, ecol, eval, offs, pooled);

    // Gathered GEMM + bias + ELU (B in LDS, XCD-pinned by batch,
    // 8 waves x 32x64 tiles, 4 waves/SIMD).
    spiral_mfma<<<B * MT, 512, 0, stream>>>(pooled,
        reinterpret_cast<const bf16x8*>(packedW), sp, bias, out);
}